// Round 3
// baseline (1828.713 us; speedup 1.0000x reference)
//
#include <hip/hip_runtime.h>
#include <hip/hip_bf16.h>

#define NROWS 16384   // B*T
#define FEATD 256
#define F1D   512
#define SZD   192     // action_dim * atoms

__device__ __forceinline__ float sigmoid_f(float x) { return 1.0f / (1.0f + expf(-x)); }

__device__ __forceinline__ float gelu_f(float x) {
    // jax.nn.gelu approximate=True (tanh form)
    float x3 = x * x * x;
    float inner = 0.7978845608028654f * (x + 0.044715f * x3);
    return 0.5f * x * (1.0f + tanhf(inner));
}

// ---------------------------------------------------------------------------
// prep: W1 = tanh(Wh1)*sig(Mh1); W2 = tanh(Wh2)*sig(Mh2)
// ---------------------------------------------------------------------------
__global__ void prep_kernel(const float* __restrict__ Wh1, const float* __restrict__ Mh1,
                            const float* __restrict__ Wh2, const float* __restrict__ Mh2,
                            float* __restrict__ W1, float* __restrict__ W2)
{
    int idx = blockIdx.x * blockDim.x + threadIdx.x;
    if (idx < FEATD * F1D)
        W1[idx] = tanhf(Wh1[idx]) * sigmoid_f(Mh1[idx]);
    if (idx < F1D * F1D)
        W2[idx] = tanhf(Wh2[idx]) * sigmoid_f(Mh2[idx]);
}

// per-column nonzero row range of w [512,192] (block-sparse, <=3 rows/col)
__global__ void colrange_kernel(const float* __restrict__ w, int* __restrict__ cs,
                                int* __restrict__ ce, int ncols)
{
    int c = blockIdx.x * blockDim.x + threadIdx.x;
    if (c >= ncols) return;
    int s = 0, e = -1;
    for (int r = 0; r < F1D; ++r) {
        if (w[(size_t)r * ncols + c] != 0.0f) { if (e < 0) s = r; e = r; }
    }
    cs[c] = s; ce[c] = e;
}

// ---------------------------------------------------------------------------
// Fused NALU layer: 3 GEMMs sharing tiles + full epilogue.
//   a = x1@W ; m = exp(clip(log(|x2|+1e-7)@W)) ; g = sigmoid(x1@G)
//   out1 = gelu(a) ; h12 = gelu(g*a+(1-g)*m)
//   out2 = WRITE_LOG ? log(|h12|+1e-7) : h12
// ---------------------------------------------------------------------------
template<int K, bool LOGX2, bool WRITE_LOG>
__global__ __launch_bounds__(256)
void nalu_kernel(const float* __restrict__ x1, const float* __restrict__ x2,
                 const float* __restrict__ W,  const float* __restrict__ G,
                 float* __restrict__ out1, float* __restrict__ out2, int ld_out)
{
    constexpr int BM = 64, BN = 64, BK = 16, PAD = 4;
    __shared__ float As1[BK][BM + PAD];
    __shared__ float As2[BK][BM + PAD];
    __shared__ float BsW[BK][BN + PAD];
    __shared__ float BsG[BK][BN + PAD];

    const int tid = threadIdx.x;
    const int tx = tid & 15, ty = tid >> 4;
    const int col0 = blockIdx.x * BN;
    const int row0 = blockIdx.y * BM;

    float acc_a[4][4] = {}, acc_m[4][4] = {}, acc_g[4][4] = {};

    const int ar = tid >> 2;        // 0..63 row in A tile
    const int ac = (tid & 3) * 4;   // k offset in A tile
    const int br = tid >> 4;        // 0..15 k in B tile
    const int bc = (tid & 15) * 4;  // col offset in B tile

    for (int k0 = 0; k0 < K; k0 += BK) {
        float4 v1 = *(const float4*)(x1 + (size_t)(row0 + ar) * K + k0 + ac);
        float4 v2 = *(const float4*)(x2 + (size_t)(row0 + ar) * K + k0 + ac);
        if (LOGX2) {
            v2.x = logf(fabsf(v2.x) + 1e-7f);
            v2.y = logf(fabsf(v2.y) + 1e-7f);
            v2.z = logf(fabsf(v2.z) + 1e-7f);
            v2.w = logf(fabsf(v2.w) + 1e-7f);
        }
        float4 wv = *(const float4*)(W + (size_t)(k0 + br) * F1D + col0 + bc);
        float4 gv = *(const float4*)(G + (size_t)(k0 + br) * F1D + col0 + bc);
        __syncthreads();   // protect previous iteration's reads
        As1[ac + 0][ar] = v1.x; As1[ac + 1][ar] = v1.y;
        As1[ac + 2][ar] = v1.z; As1[ac + 3][ar] = v1.w;
        As2[ac + 0][ar] = v2.x; As2[ac + 1][ar] = v2.y;
        As2[ac + 2][ar] = v2.z; As2[ac + 3][ar] = v2.w;
        *(float4*)&BsW[br][bc] = wv;
        *(float4*)&BsG[br][bc] = gv;
        __syncthreads();
        #pragma unroll
        for (int k = 0; k < BK; ++k) {
            float4 a1 = *(const float4*)&As1[k][ty * 4];
            float4 a2 = *(const float4*)&As2[k][ty * 4];
            float4 bw = *(const float4*)&BsW[k][tx * 4];
            float4 bg = *(const float4*)&BsG[k][tx * 4];
            float a1v[4] = {a1.x, a1.y, a1.z, a1.w};
            float a2v[4] = {a2.x, a2.y, a2.z, a2.w};
            float bwv[4] = {bw.x, bw.y, bw.z, bw.w};
            float bgv[4] = {bg.x, bg.y, bg.z, bg.w};
            #pragma unroll
            for (int i = 0; i < 4; ++i)
                #pragma unroll
                for (int j = 0; j < 4; ++j) {
                    acc_a[i][j] = fmaf(a1v[i], bwv[j], acc_a[i][j]);
                    acc_m[i][j] = fmaf(a2v[i], bwv[j], acc_m[i][j]);
                    acc_g[i][j] = fmaf(a1v[i], bgv[j], acc_g[i][j]);
                }
        }
    }

    #pragma unroll
    for (int i = 0; i < 4; ++i) {
        int row = row0 + ty * 4 + i;
        float o1v[4], o2v[4];
        #pragma unroll
        for (int j = 0; j < 4; ++j) {
            float a  = acc_a[i][j];
            float mm = acc_m[i][j];
            float g  = acc_g[i][j];
            float m_ = expf(fminf(fmaxf(mm, -20.0f), 20.0f));
            float gs = sigmoid_f(g);
            float h11v = gelu_f(a);
            float h12v = gelu_f(gs * a + (1.0f - gs) * m_);
            o1v[j] = h11v;
            o2v[j] = WRITE_LOG ? logf(fabsf(h12v) + 1e-7f) : h12v;
        }
        float* p1 = out1 + (size_t)row * ld_out + col0 + tx * 4;
        float* p2 = out2 + (size_t)row * ld_out + col0 + tx * 4;
        *(float4*)p1 = make_float4(o1v[0], o1v[1], o1v[2], o1v[3]);
        *(float4*)p2 = make_float4(o2v[0], o2v[1], o2v[2], o2v[3]);
    }
}

// ---------------------------------------------------------------------------
// plain GEMM + bias: out[M,512] = A[M,K] @ B[K,512] + bias
// ---------------------------------------------------------------------------
template<int K>
__global__ __launch_bounds__(256)
void gemm_bias_kernel(const float* __restrict__ A, const float* __restrict__ B,
                      const float* __restrict__ bias, float* __restrict__ out)
{
    constexpr int BM = 64, BN = 64, BK = 16, PAD = 4;
    __shared__ float As[BK][BM + PAD];
    __shared__ float Bs[BK][BN + PAD];

    const int tid = threadIdx.x;
    const int tx = tid & 15, ty = tid >> 4;
    const int col0 = blockIdx.x * BN;
    const int row0 = blockIdx.y * BM;

    float acc[4][4] = {};

    const int ar = tid >> 2;
    const int ac = (tid & 3) * 4;
    const int br = tid >> 4;
    const int bc = (tid & 15) * 4;

    for (int k0 = 0; k0 < K; k0 += BK) {
        float4 va = *(const float4*)(A + (size_t)(row0 + ar) * K + k0 + ac);
        float4 vb = *(const float4*)(B + (size_t)(k0 + br) * F1D + col0 + bc);
        __syncthreads();
        As[ac + 0][ar] = va.x; As[ac + 1][ar] = va.y;
        As[ac + 2][ar] = va.z; As[ac + 3][ar] = va.w;
        *(float4*)&Bs[br][bc] = vb;
        __syncthreads();
        #pragma unroll
        for (int k = 0; k < BK; ++k) {
            float4 a = *(const float4*)&As[k][ty * 4];
            float4 b = *(const float4*)&Bs[k][tx * 4];
            float av[4] = {a.x, a.y, a.z, a.w};
            float bv[4] = {b.x, b.y, b.z, b.w};
            #pragma unroll
            for (int i = 0; i < 4; ++i)
                #pragma unroll
                for (int j = 0; j < 4; ++j)
                    acc[i][j] = fmaf(av[i], bv[j], acc[i][j]);
        }
    }

    float4 bias4 = *(const float4*)(bias + col0 + tx * 4);
    float bv[4] = {bias4.x, bias4.y, bias4.z, bias4.w};
    #pragma unroll
    for (int i = 0; i < 4; ++i) {
        int row = row0 + ty * 4 + i;
        float ov[4];
        #pragma unroll
        for (int j = 0; j < 4; ++j) ov[j] = acc[i][j] + bv[j];
        *(float4*)(out + (size_t)row * F1D + col0 + tx * 4) =
            make_float4(ov[0], ov[1], ov[2], ov[3]);
    }
}

// xa = gelu(pre @ Keff), Keff = kron(I, kn)[:512,:512]*we computed inline
__global__ void keff_gelu_kernel(const float* __restrict__ pre, const float* __restrict__ kn,
                                 const float* __restrict__ we, float* __restrict__ out, int m)
{
    int idx = blockIdx.x * blockDim.x + threadIdx.x;
    if (idx >= NROWS * F1D) return;
    int n = idx >> 9;
    int j = idx & 511;
    int jb = (j / m) * m;
    int jm = j - jb;
    float s = 0.0f;
    for (int t = 0; t < m; ++t) {
        int i = jb + t;
        if (i < F1D) {
            float kv = kn[t * m + jm] * we[(size_t)i * F1D + j];
            s = fmaf(pre[(size_t)n * F1D + i], kv, s);
        }
    }
    out[idx] = gelu_f(s);
}

// v = xa2 @ (W3*we) + b3 ; W3*we banded (|i-j|<=7 is a safe superset; we blocks <=3)
__global__ void v_kernel(const float* __restrict__ xa2, const float* __restrict__ W3,
                         const float* __restrict__ we, const float* __restrict__ b3,
                         float* __restrict__ vout)
{
    int idx = blockIdx.x * blockDim.x + threadIdx.x;
    if (idx >= NROWS * F1D) return;
    int n = idx >> 9;
    int j = idx & 511;
    float s = b3[j];
    int lo = j - 7; if (lo < 0) lo = 0;
    int hi = j + 7; if (hi > F1D - 1) hi = F1D - 1;
    for (int i = lo; i <= hi; ++i) {
        float wv = W3[(size_t)i * F1D + j] * we[(size_t)i * F1D + j];
        s = fmaf(xa2[(size_t)n * F1D + i], wv, s);
    }
    vout[idx] = s;
}

// o = xa1 @ w with per-column nonzero row range
__global__ void o_kernel(const float* __restrict__ xa1, const float* __restrict__ w,
                         const int* __restrict__ cs, const int* __restrict__ ce,
                         float* __restrict__ oout)
{
    int idx = blockIdx.x * blockDim.x + threadIdx.x;
    if (idx >= NROWS * SZD) return;
    int n = idx / SZD;
    int c = idx - n * SZD;
    float s = 0.0f;
    int e = ce[c];
    for (int r = cs[c]; r <= e; ++r)
        s = fmaf(xa1[(size_t)n * F1D + r], w[(size_t)r * SZD + c], s);
    oout[idx] = s;
}

extern "C" void kernel_launch(void* const* d_in, const int* in_sizes, int n_in,
                              void* d_out, int out_size, void* d_ws, size_t ws_size,
                              hipStream_t stream)
{
    const float* features = (const float*)d_in[0];
    const float* Wh1 = (const float*)d_in[1];
    const float* Mh1 = (const float*)d_in[2];
    const float* G1  = (const float*)d_in[3];
    const float* Wh2 = (const float*)d_in[4];
    const float* Mh2 = (const float*)d_in[5];
    const float* G2  = (const float*)d_in[6];
    const float* W1e = (const float*)d_in[7];
    const float* b1e = (const float*)d_in[8];
    const float* W2e = (const float*)d_in[9];
    const float* b2e = (const float*)d_in[10];
    const float* W3  = (const float*)d_in[11];
    const float* b3  = (const float*)d_in[12];
    const float* kn  = (const float*)d_in[13];
    const float* w   = (const float*)d_in[14];
    const float* we  = (const float*)d_in[15];

    int m = 1;
    { int s = in_sizes[13]; while (m * m < s) ++m; }   // m = sqrt(|kn|)

    // workspace layout (~136 MB peak; xa1 lives in d_out's v-region)
    float* ws = (float*)d_ws;
    size_t off = 0;
    auto alloc = [&](size_t n) { float* p = ws + off; off += n; return p; };
    float* W1   = alloc((size_t)FEATD * F1D);
    float* W2   = alloc((size_t)F1D * F1D);
    float* h11  = alloc((size_t)NROWS * F1D);     // later reused as pre1
    float* lh12 = alloc((size_t)NROWS * F1D);     // later reused as pre2
    float* h    = alloc((size_t)NROWS * 2 * F1D); // later: first half reused as xa2
    int* cs = (int*)(ws + off); off += SZD;
    int* ce = (int*)(ws + off); off += SZD;

    float* o_out = (float*)d_out;
    float* v_out = (float*)d_out + (size_t)NROWS * SZD;
    float* xa1   = v_out;   // scratch in output; fully overwritten by v_kernel at the end

    prep_kernel<<<(F1D * F1D + 255) / 256, 256, 0, stream>>>(Wh1, Mh1, Wh2, Mh2, W1, W2);
    colrange_kernel<<<1, 256, 0, stream>>>(w, cs, ce, SZD);

    dim3 gG(F1D / 64, NROWS / 64);   // (8, 256)

    // layer 1: x1 = x2 = features (log applied at load)
    nalu_kernel<FEATD, true, true><<<gG, 256, 0, stream>>>(
        features, features, W1, G1, h11, lh12, F1D);
    // layer 2: outputs concatenated into h [N,1024]
    nalu_kernel<F1D, false, false><<<gG, 256, 0, stream>>>(
        h11, lh12, W2, G2, h, h + F1D, 2 * F1D);

    // fc1e: pre1 = h @ W1e + b1e   (pre1 reuses h11, dead after layer 2)
    float* pre1 = h11;
    gemm_bias_kernel<2 * F1D><<<gG, 256, 0, stream>>>(h, W1e, b1e, pre1);

    int totF = NROWS * F1D;
    keff_gelu_kernel<<<(totF + 255) / 256, 256, 0, stream>>>(pre1, kn, we, xa1, m);

    // fc2e: pre2 = xa1 @ W2e + b2e  (pre2 reuses lh12)
    float* pre2 = lh12;
    gemm_bias_kernel<F1D><<<gG, 256, 0, stream>>>(xa1, W2e, b2e, pre2);

    float* xa2 = h;   // h dead after fc1e GEMM
    keff_gelu_kernel<<<(totF + 255) / 256, 256, 0, stream>>>(pre2, kn, we, xa2, m);

    // o BEFORE v: v_kernel's write fully overwrites xa1's scratch region
    int totO = NROWS * SZD;
    o_kernel<<<(totO + 255) / 256, 256, 0, stream>>>(xa1, w, cs, ce, o_out);
    v_kernel<<<(totF + 255) / 256, 256, 0, stream>>>(xa2, W3, we, b3, v_out);
}

// Round 4
// 1042.472 us; speedup vs baseline: 1.7542x; 1.7542x over previous
//
#include <hip/hip_runtime.h>
#include <hip/hip_bf16.h>

#define NROWS 16384   // B*T
#define FEATD 256
#define F1D   512
#define SZD   192     // action_dim * atoms

__device__ __forceinline__ float sigmoid_f(float x) { return 1.0f / (1.0f + expf(-x)); }

__device__ __forceinline__ float gelu_f(float x) {
    // jax.nn.gelu approximate=True (tanh form)
    float x3 = x * x * x;
    float inner = 0.7978845608028654f * (x + 0.044715f * x3);
    return 0.5f * x * (1.0f + tanhf(inner));
}

// ---------------------------------------------------------------------------
// prep: W1 = tanh(Wh1)*sig(Mh1); W2 = tanh(Wh2)*sig(Mh2)
// ---------------------------------------------------------------------------
__global__ void prep_kernel(const float* __restrict__ Wh1, const float* __restrict__ Mh1,
                            const float* __restrict__ Wh2, const float* __restrict__ Mh2,
                            float* __restrict__ W1, float* __restrict__ W2)
{
    int idx = blockIdx.x * blockDim.x + threadIdx.x;
    if (idx < FEATD * F1D)
        W1[idx] = tanhf(Wh1[idx]) * sigmoid_f(Mh1[idx]);
    if (idx < F1D * F1D)
        W2[idx] = tanhf(Wh2[idx]) * sigmoid_f(Mh2[idx]);
}

// ---------------------------------------------------------------------------
// band compaction (one-time, tiny):
//   Kb[t][j]  = kron(I,kn)[jb+t][j] * we[jb+t][j],  jb=(j/m)*m, t<4 (zero-pad)
//   W3b[d][j] = (W3*we)[j-7+d][j], d<15 (zero outside [0,512))
// ---------------------------------------------------------------------------
__global__ __launch_bounds__(512)
void prep2_kernel(const float* __restrict__ kn, const float* __restrict__ we,
                  const float* __restrict__ W3,
                  float* __restrict__ Kb, float* __restrict__ W3b, int m)
{
    int j = threadIdx.x;
    if (j >= F1D) return;
    int jb = (j / m) * m;
    int jm = j - jb;
    for (int t = 0; t < 4; ++t) {
        int i = jb + t;
        float v = 0.0f;
        if (t < m && i < F1D)
            v = kn[t * m + jm] * we[(size_t)i * F1D + j];
        Kb[t * F1D + j] = v;
    }
    for (int d = 0; d < 15; ++d) {
        int i = j - 7 + d;
        float v = 0.0f;
        if (i >= 0 && i < F1D)
            v = W3[(size_t)i * F1D + j] * we[(size_t)i * F1D + j];
        W3b[d * F1D + j] = v;
    }
}

// per-column nonzero row range of w [512,192] + compact band wb[4][192]
__global__ void colrange_wband_kernel(const float* __restrict__ w, int* __restrict__ cs,
                                      float* __restrict__ wb)
{
    int c = blockIdx.x * blockDim.x + threadIdx.x;
    if (c >= SZD) return;
    int s = 0, e = -1;
    for (int r = 0; r < F1D; ++r) {
        if (w[(size_t)r * SZD + c] != 0.0f) { if (e < 0) s = r; e = r; }
    }
    cs[c] = s;
    for (int t = 0; t < 4; ++t)
        wb[t * SZD + c] = (s + t <= e) ? w[(size_t)(s + t) * SZD + c] : 0.0f;
}

// ---------------------------------------------------------------------------
// Fused NALU layer: 3 GEMMs sharing tiles + full epilogue.
// ---------------------------------------------------------------------------
template<int K, bool LOGX2, bool WRITE_LOG>
__global__ __launch_bounds__(256)
void nalu_kernel(const float* __restrict__ x1, const float* __restrict__ x2,
                 const float* __restrict__ W,  const float* __restrict__ G,
                 float* __restrict__ out1, float* __restrict__ out2, int ld_out)
{
    constexpr int BM = 64, BN = 64, BK = 16, PAD = 4;
    __shared__ float As1[BK][BM + PAD];
    __shared__ float As2[BK][BM + PAD];
    __shared__ float BsW[BK][BN + PAD];
    __shared__ float BsG[BK][BN + PAD];

    const int tid = threadIdx.x;
    const int tx = tid & 15, ty = tid >> 4;
    const int col0 = blockIdx.x * BN;
    const int row0 = blockIdx.y * BM;

    float acc_a[4][4] = {}, acc_m[4][4] = {}, acc_g[4][4] = {};

    const int ar = tid >> 2;        // 0..63 row in A tile
    const int ac = (tid & 3) * 4;   // k offset in A tile
    const int br = tid >> 4;        // 0..15 k in B tile
    const int bc = (tid & 15) * 4;  // col offset in B tile

    for (int k0 = 0; k0 < K; k0 += BK) {
        float4 v1 = *(const float4*)(x1 + (size_t)(row0 + ar) * K + k0 + ac);
        float4 v2 = *(const float4*)(x2 + (size_t)(row0 + ar) * K + k0 + ac);
        if (LOGX2) {
            v2.x = logf(fabsf(v2.x) + 1e-7f);
            v2.y = logf(fabsf(v2.y) + 1e-7f);
            v2.z = logf(fabsf(v2.z) + 1e-7f);
            v2.w = logf(fabsf(v2.w) + 1e-7f);
        }
        float4 wv = *(const float4*)(W + (size_t)(k0 + br) * F1D + col0 + bc);
        float4 gv = *(const float4*)(G + (size_t)(k0 + br) * F1D + col0 + bc);
        __syncthreads();   // protect previous iteration's reads
        As1[ac + 0][ar] = v1.x; As1[ac + 1][ar] = v1.y;
        As1[ac + 2][ar] = v1.z; As1[ac + 3][ar] = v1.w;
        As2[ac + 0][ar] = v2.x; As2[ac + 1][ar] = v2.y;
        As2[ac + 2][ar] = v2.z; As2[ac + 3][ar] = v2.w;
        *(float4*)&BsW[br][bc] = wv;
        *(float4*)&BsG[br][bc] = gv;
        __syncthreads();
        #pragma unroll
        for (int k = 0; k < BK; ++k) {
            float4 a1 = *(const float4*)&As1[k][ty * 4];
            float4 a2 = *(const float4*)&As2[k][ty * 4];
            float4 bw = *(const float4*)&BsW[k][tx * 4];
            float4 bg = *(const float4*)&BsG[k][tx * 4];
            float a1v[4] = {a1.x, a1.y, a1.z, a1.w};
            float a2v[4] = {a2.x, a2.y, a2.z, a2.w};
            float bwv[4] = {bw.x, bw.y, bw.z, bw.w};
            float bgv[4] = {bg.x, bg.y, bg.z, bg.w};
            #pragma unroll
            for (int i = 0; i < 4; ++i)
                #pragma unroll
                for (int j = 0; j < 4; ++j) {
                    acc_a[i][j] = fmaf(a1v[i], bwv[j], acc_a[i][j]);
                    acc_m[i][j] = fmaf(a2v[i], bwv[j], acc_m[i][j]);
                    acc_g[i][j] = fmaf(a1v[i], bgv[j], acc_g[i][j]);
                }
        }
    }

    #pragma unroll
    for (int i = 0; i < 4; ++i) {
        int row = row0 + ty * 4 + i;
        float o1v[4], o2v[4];
        #pragma unroll
        for (int j = 0; j < 4; ++j) {
            float a  = acc_a[i][j];
            float mm = acc_m[i][j];
            float g  = acc_g[i][j];
            float m_ = expf(fminf(fmaxf(mm, -20.0f), 20.0f));
            float gs = sigmoid_f(g);
            float h11v = gelu_f(a);
            float h12v = gelu_f(gs * a + (1.0f - gs) * m_);
            o1v[j] = h11v;
            o2v[j] = WRITE_LOG ? logf(fabsf(h12v) + 1e-7f) : h12v;
        }
        float* p1 = out1 + (size_t)row * ld_out + col0 + tx * 4;
        float* p2 = out2 + (size_t)row * ld_out + col0 + tx * 4;
        *(float4*)p1 = make_float4(o1v[0], o1v[1], o1v[2], o1v[3]);
        *(float4*)p2 = make_float4(o2v[0], o2v[1], o2v[2], o2v[3]);
    }
}

// ---------------------------------------------------------------------------
// plain GEMM + bias: out[M,512] = A[M,K] @ B[K,512] + bias
// ---------------------------------------------------------------------------
template<int K>
__global__ __launch_bounds__(256)
void gemm_bias_kernel(const float* __restrict__ A, const float* __restrict__ B,
                      const float* __restrict__ bias, float* __restrict__ out)
{
    constexpr int BM = 64, BN = 64, BK = 16, PAD = 4;
    __shared__ float As[BK][BM + PAD];
    __shared__ float Bs[BK][BN + PAD];

    const int tid = threadIdx.x;
    const int tx = tid & 15, ty = tid >> 4;
    const int col0 = blockIdx.x * BN;
    const int row0 = blockIdx.y * BM;

    float acc[4][4] = {};

    const int ar = tid >> 2;
    const int ac = (tid & 3) * 4;
    const int br = tid >> 4;
    const int bc = (tid & 15) * 4;

    for (int k0 = 0; k0 < K; k0 += BK) {
        float4 va = *(const float4*)(A + (size_t)(row0 + ar) * K + k0 + ac);
        float4 vb = *(const float4*)(B + (size_t)(k0 + br) * F1D + col0 + bc);
        __syncthreads();
        As[ac + 0][ar] = va.x; As[ac + 1][ar] = va.y;
        As[ac + 2][ar] = va.z; As[ac + 3][ar] = va.w;
        *(float4*)&Bs[br][bc] = vb;
        __syncthreads();
        #pragma unroll
        for (int k = 0; k < BK; ++k) {
            float4 a = *(const float4*)&As[k][ty * 4];
            float4 b = *(const float4*)&Bs[k][tx * 4];
            float av[4] = {a.x, a.y, a.z, a.w};
            float bv[4] = {b.x, b.y, b.z, b.w};
            #pragma unroll
            for (int i = 0; i < 4; ++i)
                #pragma unroll
                for (int j = 0; j < 4; ++j)
                    acc[i][j] = fmaf(av[i], bv[j], acc[i][j]);
        }
    }

    float4 bias4 = *(const float4*)(bias + col0 + tx * 4);
    float bv[4] = {bias4.x, bias4.y, bias4.z, bias4.w};
    #pragma unroll
    for (int i = 0; i < 4; ++i) {
        int row = row0 + ty * 4 + i;
        float ov[4];
        #pragma unroll
        for (int j = 0; j < 4; ++j) ov[j] = acc[i][j] + bv[j];
        *(float4*)(out + (size_t)row * F1D + col0 + tx * 4) =
            make_float4(ov[0], ov[1], ov[2], ov[3]);
    }
}

// ---------------------------------------------------------------------------
// Fused: xa1 = gelu(pre1 @ Keff) [written to global for fc2e]
//        o   = xa1 @ w           [band, from LDS]
// Block handles ROWS rows in CHUNK=2 row slices; all HBM accesses coalesced.
// ---------------------------------------------------------------------------
template<int ROWS>
__global__ __launch_bounds__(256)
void kxo_kernel(const float* __restrict__ pre1, const float* __restrict__ Kb,
                const float* __restrict__ wb, const int* __restrict__ cs,
                float* __restrict__ xa1, float* __restrict__ o_out, int m)
{
    __shared__ float sKb[4][F1D];      // 8 KB
    __shared__ float swb[4][SZD];      // 3 KB
    __shared__ int   scs[SZD];
    __shared__ float spre[2][F1D];     // 4 KB
    __shared__ float sxa[2][F1D];      // 4 KB

    const int t = threadIdx.x;
    for (int i = t; i < 4 * F1D; i += 256) sKb[i >> 9][i & 511] = Kb[i];
    for (int i = t; i < 4 * SZD; i += 256) swb[i / SZD][i % SZD] = wb[i];
    if (t < SZD) scs[t] = cs[t];

    const int row_base = blockIdx.x * ROWS;
    const int rr = t >> 7;             // 0..1 (row within chunk)
    const int jc = t & 127;            // column lane

    for (int ch = 0; ch < ROWS; ch += 2) {
        const int r0 = row_base + ch;
        __syncthreads();               // bands ready (first iter) / prev chunk done
        ((float4*)&spre[0][0])[t] = *(const float4*)(pre1 + (size_t)r0 * F1D + t * 4);
        __syncthreads();

        #pragma unroll
        for (int kk = 0; kk < 4; ++kk) {
            int j  = jc + (kk << 7);
            int jb = (j / m) * m;
            float s = 0.0f;
            for (int tt = 0; tt < 4; ++tt) {     // Kb zero-padded to 4 taps
                int i2 = jb + tt; if (i2 > F1D - 1) i2 = F1D - 1;
                s = fmaf(spre[rr][i2], sKb[tt][j], s);
            }
            float g = gelu_f(s);
            sxa[rr][j] = g;
            xa1[(size_t)(r0 + rr) * F1D + j] = g;
        }
        __syncthreads();

        for (int pos = t; pos < 2 * SZD; pos += 256) {
            int rr2 = pos / SZD, c = pos - rr2 * SZD;
            int s0 = scs[c];
            float s = 0.0f;
            #pragma unroll
            for (int tt = 0; tt < 4; ++tt) {     // wb zero-padded
                int i2 = s0 + tt; if (i2 > F1D - 1) i2 = F1D - 1;
                s = fmaf(sxa[rr2][i2], swb[tt][c], s);
            }
            o_out[(size_t)(r0 + rr2) * SZD + c] = s;
        }
    }
}

// ---------------------------------------------------------------------------
// Fused: xa2 = gelu(pre2 @ Keff) [LDS only — never touches HBM]
//        v   = xa2 @ (W3*we) + b3
// ---------------------------------------------------------------------------
template<int ROWS>
__global__ __launch_bounds__(256)
void kv_kernel(const float* __restrict__ pre2, const float* __restrict__ Kb,
               const float* __restrict__ W3b, const float* __restrict__ b3,
               float* __restrict__ v_out, int m)
{
    __shared__ float sW3[15][F1D];     // 30 KB
    __shared__ float sKb[4][F1D];      // 8 KB
    __shared__ float sb3[F1D];         // 2 KB
    __shared__ float spre[2][F1D];     // 4 KB
    __shared__ float sxa[2][F1D];      // 4 KB

    const int t = threadIdx.x;
    for (int i = t; i < 15 * F1D; i += 256) sW3[i >> 9][i & 511] = W3b[i];
    for (int i = t; i < 4 * F1D; i += 256)  sKb[i >> 9][i & 511] = Kb[i];
    for (int i = t; i < F1D; i += 256)      sb3[i] = b3[i];

    const int row_base = blockIdx.x * ROWS;
    const int rr = t >> 7;
    const int jc = t & 127;

    for (int ch = 0; ch < ROWS; ch += 2) {
        const int r0 = row_base + ch;
        __syncthreads();
        ((float4*)&spre[0][0])[t] = *(const float4*)(pre2 + (size_t)r0 * F1D + t * 4);
        __syncthreads();

        #pragma unroll
        for (int kk = 0; kk < 4; ++kk) {
            int j  = jc + (kk << 7);
            int jb = (j / m) * m;
            float s = 0.0f;
            for (int tt = 0; tt < 4; ++tt) {
                int i2 = jb + tt; if (i2 > F1D - 1) i2 = F1D - 1;
                s = fmaf(spre[rr][i2], sKb[tt][j], s);
            }
            sxa[rr][j] = gelu_f(s);
        }
        __syncthreads();

        #pragma unroll
        for (int kk = 0; kk < 4; ++kk) {
            int j = jc + (kk << 7);
            float s = sb3[j];
            #pragma unroll
            for (int d = 0; d < 15; ++d) {       // sW3 zero outside valid band
                int i2 = j - 7 + d;
                if (i2 < 0) i2 = 0; if (i2 > F1D - 1) i2 = F1D - 1;
                s = fmaf(sxa[rr][i2], sW3[d][j], s);
            }
            v_out[(size_t)(r0 + rr) * F1D + j] = s;
        }
    }
}

extern "C" void kernel_launch(void* const* d_in, const int* in_sizes, int n_in,
                              void* d_out, int out_size, void* d_ws, size_t ws_size,
                              hipStream_t stream)
{
    const float* features = (const float*)d_in[0];
    const float* Wh1 = (const float*)d_in[1];
    const float* Mh1 = (const float*)d_in[2];
    const float* G1  = (const float*)d_in[3];
    const float* Wh2 = (const float*)d_in[4];
    const float* Mh2 = (const float*)d_in[5];
    const float* G2  = (const float*)d_in[6];
    const float* W1e = (const float*)d_in[7];
    const float* b1e = (const float*)d_in[8];
    const float* W2e = (const float*)d_in[9];
    const float* b2e = (const float*)d_in[10];
    const float* W3  = (const float*)d_in[11];
    const float* b3  = (const float*)d_in[12];
    const float* kn  = (const float*)d_in[13];
    const float* w   = (const float*)d_in[14];
    const float* we  = (const float*)d_in[15];

    int m = 1;
    { int s = in_sizes[13]; while (m * m < s) ++m; }   // m = sqrt(|kn|)

    // workspace (~130 MB peak; xa1 parked in d_out's v-region)
    float* ws = (float*)d_ws;
    size_t off = 0;
    auto alloc = [&](size_t n) { float* p = ws + off; off += n; return p; };
    float* W1   = alloc((size_t)FEATD * F1D);
    float* W2   = alloc((size_t)F1D * F1D);
    float* h11  = alloc((size_t)NROWS * F1D);     // later reused as pre1
    float* lh12 = alloc((size_t)NROWS * F1D);     // later reused as pre2
    float* h    = alloc((size_t)NROWS * 2 * F1D);
    float* Kb   = alloc(4 * F1D);
    float* W3b  = alloc(15 * F1D);
    float* wb   = alloc(4 * SZD);
    int* cs = (int*)(ws + off); off += SZD;

    float* o_out = (float*)d_out;
    float* v_out = (float*)d_out + (size_t)NROWS * SZD;
    float* xa1   = v_out;   // scratch in output; fully overwritten by kv_kernel

    prep_kernel<<<(F1D * F1D + 255) / 256, 256, 0, stream>>>(Wh1, Mh1, Wh2, Mh2, W1, W2);
    prep2_kernel<<<1, 512, 0, stream>>>(kn, we, W3, Kb, W3b, m);
    colrange_wband_kernel<<<1, 256, 0, stream>>>(w, cs, wb);

    dim3 gG(F1D / 64, NROWS / 64);   // (8, 256)

    // layer 1: x1 = x2 = features (log applied at load)
    nalu_kernel<FEATD, true, true><<<gG, 256, 0, stream>>>(
        features, features, W1, G1, h11, lh12, F1D);
    // layer 2: outputs concatenated into h [N,1024]
    nalu_kernel<F1D, false, false><<<gG, 256, 0, stream>>>(
        h11, lh12, W2, G2, h, h + F1D, 2 * F1D);

    // fc1e: pre1 = h @ W1e + b1e
    float* pre1 = h11;
    gemm_bias_kernel<2 * F1D><<<gG, 256, 0, stream>>>(h, W1e, b1e, pre1);

    // fused keff_gelu + o  (writes xa1 into v-region, o into d_out)
    constexpr int ROWS = 8;
    kxo_kernel<ROWS><<<NROWS / ROWS, 256, 0, stream>>>(pre1, Kb, wb, cs, xa1, o_out, m);

    // fc2e: pre2 = xa1 @ W2e + b2e
    float* pre2 = lh12;
    gemm_bias_kernel<F1D><<<gG, 256, 0, stream>>>(xa1, W2e, b2e, pre2);

    // fused keff_gelu + v  (xa2 lives only in LDS; v overwrites xa1 scratch)
    kv_kernel<ROWS><<<NROWS / ROWS, 256, 0, stream>>>(pre2, Kb, W3b, b3, v_out, m);
}

// Round 9
// 568.110 us; speedup vs baseline: 3.2189x; 1.8350x over previous
//
#include <hip/hip_runtime.h>
#include <hip/hip_bf16.h>
#include <hip/hip_fp16.h>

#define NROWS 16384   // B*T
#define FEATD 256
#define F1D   512
#define SZD   192     // action_dim * atoms

typedef unsigned short u16;
typedef float    f32x4  __attribute__((ext_vector_type(4)));
typedef short    bf16x8 __attribute__((ext_vector_type(8)));
typedef _Float16 f16x8  __attribute__((ext_vector_type(8)));
typedef unsigned short u16x8 __attribute__((ext_vector_type(8)));

#define LO_SCALE 2048.0f
#define LO_INV   (1.0f / 2048.0f)

__device__ __forceinline__ float sigmoid_f(float x) { return 1.0f / (1.0f + expf(-x)); }

__device__ __forceinline__ float gelu_f(float x) {
    // jax.nn.gelu approximate=True (tanh form)
    float x3 = x * x * x;
    float inner = 0.7978845608028654f * (x + 0.044715f * x3);
    return 0.5f * x * (1.0f + tanhf(inner));
}

// ---- bf16 helpers (fc1e/fc2e path: range-safe for huge h values) ----
__device__ __forceinline__ u16 f2bf(float f) {
    unsigned u = __float_as_uint(f);
    u = (u + 0x7FFFu + ((u >> 16) & 1u)) >> 16;
    return (u16)u;
}
__device__ __forceinline__ float bf2f(u16 h) { return __uint_as_float(((unsigned)h) << 16); }

__device__ __forceinline__ void split8(float4 a, float4 b, u16x8& hi, u16x8& lo) {
    float v[8] = {a.x, a.y, a.z, a.w, b.x, b.y, b.z, b.w};
    #pragma unroll
    for (int i = 0; i < 8; ++i) {
        u16 h = f2bf(v[i]);
        hi[i] = h;
        lo[i] = f2bf(v[i] - bf2f(h));
    }
}

// ---- f16 scaled-split helpers (NALU path: 2^-22 rep error, denorm-proof) ----
__device__ __forceinline__ u16 f2h_u(float f)  { return __half_as_ushort(__float2half(f)); }
__device__ __forceinline__ float h2f_u(u16 u)  { return __half2float(__ushort_as_half(u)); }

// hi = f16(x); lo' = f16(2048*(x-hi))  [x-hi exact in f32; lo' always normal]
__device__ __forceinline__ void split8hs(float4 a, float4 b, u16x8& hi, u16x8& lo) {
    float v[8] = {a.x, a.y, a.z, a.w, b.x, b.y, b.z, b.w};
    #pragma unroll
    for (int i = 0; i < 8; ++i) {
        u16 h = f2h_u(v[i]);
        hi[i] = h;
        lo[i] = f2h_u((v[i] - h2f_u(h)) * LO_SCALE);
    }
}

// LDS offset (in halves) for 64B rows (32 halves) with XOR slot swizzle:
// 16B chunk c of row r stored at slot c^((r>>1)&3)  -> frag reads are 2-way max
__device__ __forceinline__ int lofs(int row, int chunk) {
    return row * 32 + ((chunk ^ ((row >> 1) & 3)) << 3);
}

// ---------------------------------------------------------------------------
// weight prep (f16 scaled-split): transpose to [N][K]; optional tanh*sig fuse
// ---------------------------------------------------------------------------
__global__ void wprep_f16_kernel(const float* __restrict__ src, const float* __restrict__ src2,
                                 u16* __restrict__ dhi, u16* __restrict__ dlo, int Kd, int Nd)
{
    int idx = blockIdx.x * blockDim.x + threadIdx.x;
    if (idx >= Kd * Nd) return;
    int n = idx / Kd, k = idx - n * Kd;
    float v = src[(size_t)k * Nd + n];
    if (src2) v = tanhf(v) * sigmoid_f(src2[(size_t)k * Nd + n]);
    u16 h = f2h_u(v);
    dhi[idx] = h;
    dlo[idx] = f2h_u((v - h2f_u(h)) * LO_SCALE);
}

// weight prep (bf16 split): for fc1e/fc2e weights
__global__ void wprep2_kernel(const float* __restrict__ src,
                              u16* __restrict__ dhi, u16* __restrict__ dlo, int Kd, int Nd)
{
    int idx = blockIdx.x * blockDim.x + threadIdx.x;
    if (idx >= Kd * Nd) return;
    int n = idx / Kd, k = idx - n * Kd;
    float v = src[(size_t)k * Nd + n];
    u16 h = f2bf(v);
    dhi[idx] = h;
    dlo[idx] = f2bf(v - bf2f(h));
}

// band compaction: Kb[t][j] = kron(I,kn)*we band (4 taps, zero-pad);
//                  W3b[d][j] = (W3*we)[j-7+d][j] (15 taps)
__global__ __launch_bounds__(512)
void prep2_kernel(const float* __restrict__ kn, const float* __restrict__ we,
                  const float* __restrict__ W3,
                  float* __restrict__ Kb, float* __restrict__ W3b, int m)
{
    int j = threadIdx.x;
    if (j >= F1D) return;
    int jb = (j / m) * m;
    int jm = j - jb;
    for (int t = 0; t < 4; ++t) {
        int i = jb + t;
        float v = 0.0f;
        if (t < m && i < F1D)
            v = kn[t * m + jm] * we[(size_t)i * F1D + j];
        Kb[t * F1D + j] = v;
    }
    for (int d = 0; d < 15; ++d) {
        int i = j - 7 + d;
        float v = 0.0f;
        if (i >= 0 && i < F1D)
            v = W3[(size_t)i * F1D + j] * we[(size_t)i * F1D + j];
        W3b[d * F1D + j] = v;
    }
}

// per-column nonzero row start of w + compact band wb[4][192]
__global__ void colrange_wband_kernel(const float* __restrict__ w, int* __restrict__ cs,
                                      float* __restrict__ wb)
{
    int c = blockIdx.x * blockDim.x + threadIdx.x;
    if (c >= SZD) return;
    int s = 0, e = -1;
    for (int r = 0; r < F1D; ++r) {
        if (w[(size_t)r * SZD + c] != 0.0f) { if (e < 0) s = r; e = r; }
    }
    cs[c] = s;
    for (int t = 0; t < 4; ++t)
        wb[t * SZD + c] = (s + t <= e) ? w[(size_t)(s + t) * SZD + c] : 0.0f;
}

// ---------------------------------------------------------------------------
// NALU layer via f16 scaled-split MFMA. Tile 64x64, 4 waves (2x2, 32x32 each).
// Per dot: acc_hh += hi@hi ; acc_x += hi@lo' + lo'@hi ; result = hh + x/2048.
// All operands range-verified f16-safe (|log| <= 20.01 by clip; acts <= ~500).
//   a = x1@W ; mm = x2log@W ; g = x1@G
//   h11 = gelu(a); h12 = gelu(sig(g)*a + (1-sig(g))*exp(clip(mm,-20,20)))
//   out1 = h11 ; out2 = WRITE_LOG ? log(|h12|+1e-7) : h12   (f32 outputs)
// ---------------------------------------------------------------------------
template<int K, bool LOGX2, bool WRITE_LOG>
__global__ __launch_bounds__(256)
void nalu_mfma_kernel(const float* __restrict__ x1, const float* __restrict__ x2,
                      const u16* __restrict__ Wh, const u16* __restrict__ Wl,
                      const u16* __restrict__ Gh, const u16* __restrict__ Gl,
                      float* __restrict__ out1, float* __restrict__ out2, int ld_out)
{
    __shared__ u16 A1h[64 * 32], A1l[64 * 32];
    __shared__ u16 A2h[64 * 32], A2l[64 * 32];
    __shared__ u16 BWh[64 * 32], BWl[64 * 32];
    __shared__ u16 BGh[64 * 32], BGl[64 * 32];

    const int t = threadIdx.x;
    const int lane = t & 63;
    const int wv = t >> 6;
    const int wr = wv >> 1, wc = wv & 1;
    const int lr = lane & 15, lk = lane >> 4;
    const int row0 = blockIdx.y * 64;
    const int col0 = blockIdx.x * 64;
    const int sr = t >> 2;      // staging row (0..63)
    const int kc = t & 3;       // staging 16B chunk

    f32x4 aA[2][2], aAx[2][2], aM[2][2], aMx[2][2], aG[2][2], aGx[2][2];
    #pragma unroll
    for (int i = 0; i < 2; ++i)
        #pragma unroll
        for (int j = 0; j < 2; ++j) {
            aA[i][j] = 0; aAx[i][j] = 0;
            aM[i][j] = 0; aMx[i][j] = 0;
            aG[i][j] = 0; aGx[i][j] = 0;
        }

    for (int k0 = 0; k0 < K; k0 += 32) {
        const float* px1 = x1 + (size_t)(row0 + sr) * K + k0 + kc * 8;
        float4 f0 = *(const float4*)px1;
        float4 f1 = *(const float4*)(px1 + 4);
        u16x8 v1h, v1l;
        split8hs(f0, f1, v1h, v1l);
        float4 e0, e1;
        if (LOGX2) {   // layer 1: x2 == x1, log applied here (f32 exact)
            e0.x = logf(fabsf(f0.x) + 1e-7f); e0.y = logf(fabsf(f0.y) + 1e-7f);
            e0.z = logf(fabsf(f0.z) + 1e-7f); e0.w = logf(fabsf(f0.w) + 1e-7f);
            e1.x = logf(fabsf(f1.x) + 1e-7f); e1.y = logf(fabsf(f1.y) + 1e-7f);
            e1.z = logf(fabsf(f1.z) + 1e-7f); e1.w = logf(fabsf(f1.w) + 1e-7f);
        } else {
            const float* px2 = x2 + (size_t)(row0 + sr) * K + k0 + kc * 8;
            e0 = *(const float4*)px2;
            e1 = *(const float4*)(px2 + 4);
        }
        u16x8 v2h, v2l;
        split8hs(e0, e1, v2h, v2l);
        u16x8 vwh = *(const u16x8*)(Wh + (size_t)(col0 + sr) * K + k0 + kc * 8);
        u16x8 vwl = *(const u16x8*)(Wl + (size_t)(col0 + sr) * K + k0 + kc * 8);
        u16x8 vgh = *(const u16x8*)(Gh + (size_t)(col0 + sr) * K + k0 + kc * 8);
        u16x8 vgl = *(const u16x8*)(Gl + (size_t)(col0 + sr) * K + k0 + kc * 8);

        __syncthreads();   // previous iteration's frag reads done
        {
            int o = lofs(sr, kc);
            *(u16x8*)&A1h[o] = v1h;  *(u16x8*)&A1l[o] = v1l;
            *(u16x8*)&A2h[o] = v2h;  *(u16x8*)&A2l[o] = v2l;
            *(u16x8*)&BWh[o] = vwh;  *(u16x8*)&BWl[o] = vwl;
            *(u16x8*)&BGh[o] = vgh;  *(u16x8*)&BGl[o] = vgl;
        }
        __syncthreads();

        #pragma unroll
        for (int fc = 0; fc < 2; ++fc) {
            const int bo = lofs(wc * 32 + fc * 16 + lr, lk);
            f16x8 bwh = *(f16x8*)&BWh[bo];
            f16x8 bwl = *(f16x8*)&BWl[bo];
            f16x8 bgh = *(f16x8*)&BGh[bo];
            f16x8 bgl = *(f16x8*)&BGl[bo];
            #pragma unroll
            for (int fr = 0; fr < 2; ++fr) {
                const int ao = lofs(wr * 32 + fr * 16 + lr, lk);
                f16x8 a1h = *(f16x8*)&A1h[ao];
                f16x8 a1l = *(f16x8*)&A1l[ao];
                f16x8 a2h = *(f16x8*)&A2h[ao];
                f16x8 a2l = *(f16x8*)&A2l[ao];
                aA [fr][fc] = __builtin_amdgcn_mfma_f32_16x16x32_f16(a1h, bwh, aA [fr][fc], 0, 0, 0);
                aAx[fr][fc] = __builtin_amdgcn_mfma_f32_16x16x32_f16(a1h, bwl, aAx[fr][fc], 0, 0, 0);
                aAx[fr][fc] = __builtin_amdgcn_mfma_f32_16x16x32_f16(a1l, bwh, aAx[fr][fc], 0, 0, 0);
                aM [fr][fc] = __builtin_amdgcn_mfma_f32_16x16x32_f16(a2h, bwh, aM [fr][fc], 0, 0, 0);
                aMx[fr][fc] = __builtin_amdgcn_mfma_f32_16x16x32_f16(a2h, bwl, aMx[fr][fc], 0, 0, 0);
                aMx[fr][fc] = __builtin_amdgcn_mfma_f32_16x16x32_f16(a2l, bwh, aMx[fr][fc], 0, 0, 0);
                aG [fr][fc] = __builtin_amdgcn_mfma_f32_16x16x32_f16(a1h, bgh, aG [fr][fc], 0, 0, 0);
                aGx[fr][fc] = __builtin_amdgcn_mfma_f32_16x16x32_f16(a1h, bgl, aGx[fr][fc], 0, 0, 0);
                aGx[fr][fc] = __builtin_amdgcn_mfma_f32_16x16x32_f16(a1l, bgh, aGx[fr][fc], 0, 0, 0);
            }
        }
    }

    #pragma unroll
    for (int fr = 0; fr < 2; ++fr)
        #pragma unroll
        for (int fc = 0; fc < 2; ++fc) {
            int colg = col0 + wc * 32 + fc * 16 + lr;
            int rowb = row0 + wr * 32 + fr * 16 + lk * 4;
            #pragma unroll
            for (int i = 0; i < 4; ++i) {
                float a  = aA[fr][fc][i] + aAx[fr][fc][i] * LO_INV;
                float mm = aM[fr][fc][i] + aMx[fr][fc][i] * LO_INV;
                float g  = aG[fr][fc][i] + aGx[fr][fc][i] * LO_INV;
                float m_ = expf(fminf(fmaxf(mm, -20.0f), 20.0f));
                float gs = sigmoid_f(g);
                float h11v = gelu_f(a);
                float h12v = gelu_f(gs * a + (1.0f - gs) * m_);
                out1[(size_t)(rowb + i) * ld_out + colg] = h11v;
                out2[(size_t)(rowb + i) * ld_out + colg] =
                    WRITE_LOG ? logf(fabsf(h12v) + 1e-7f) : h12v;
            }
        }
}

// ---------------------------------------------------------------------------
// GEMM + bias via split-bf16 MFMA (range-safe for unbounded h; no exp/log
// amplifier downstream): out_f32[M,512] = A_f32[M,K] @ B + bias
// ---------------------------------------------------------------------------
template<int K>
__global__ __launch_bounds__(256)
void gemm_mfma_kernel(const float* __restrict__ A,
                      const u16* __restrict__ Bh, const u16* __restrict__ Bl,
                      const float* __restrict__ bias, float* __restrict__ out)
{
    __shared__ u16 Ah[128 * 32], Al[128 * 32];
    __shared__ u16 Bsh[64 * 32], Bsl[64 * 32];

    const int t = threadIdx.x;
    const int lane = t & 63;
    const int wv = t >> 6;
    const int wr = wv >> 1, wc = wv & 1;
    const int lr = lane & 15, lk = lane >> 4;
    const int row0 = blockIdx.y * 128;
    const int col0 = blockIdx.x * 64;
    const int sr = t >> 2;
    const int kc = t & 3;

    f32x4 acc[4][2];
    #pragma unroll
    for (int i = 0; i < 4; ++i)
        #pragma unroll
        for (int j = 0; j < 2; ++j) acc[i][j] = 0;

    for (int k0 = 0; k0 < K; k0 += 32) {
        u16x8 vah[2], val[2];
        #pragma unroll
        for (int p = 0; p < 2; ++p) {
            int r = p * 64 + sr;
            const float* pa = A + (size_t)(row0 + r) * K + k0 + kc * 8;
            float4 f0 = *(const float4*)pa;
            float4 f1 = *(const float4*)(pa + 4);
            split8(f0, f1, vah[p], val[p]);
        }
        u16x8 vbh = *(const u16x8*)(Bh + (size_t)(col0 + sr) * K + k0 + kc * 8);
        u16x8 vbl = *(const u16x8*)(Bl + (size_t)(col0 + sr) * K + k0 + kc * 8);

        __syncthreads();
        #pragma unroll
        for (int p = 0; p < 2; ++p) {
            int o = lofs(p * 64 + sr, kc);
            *(u16x8*)&Ah[o] = vah[p];
            *(u16x8*)&Al[o] = val[p];
        }
        {
            int o = lofs(sr, kc);
            *(u16x8*)&Bsh[o] = vbh;
            *(u16x8*)&Bsl[o] = vbl;
        }
        __syncthreads();

        #pragma unroll
        for (int fc = 0; fc < 2; ++fc) {
            const int bo = lofs(wc * 32 + fc * 16 + lr, lk);
            bf16x8 bh = *(bf16x8*)&Bsh[bo];
            bf16x8 bl = *(bf16x8*)&Bsl[bo];
            #pragma unroll
            for (int fr = 0; fr < 4; ++fr) {
                const int ao = lofs(wr * 64 + fr * 16 + lr, lk);
                bf16x8 ah = *(bf16x8*)&Ah[ao];
                bf16x8 al = *(bf16x8*)&Al[ao];
                f32x4 a = acc[fr][fc];
                a = __builtin_amdgcn_mfma_f32_16x16x32_bf16(ah, bh, a, 0, 0, 0);
                a = __builtin_amdgcn_mfma_f32_16x16x32_bf16(ah, bl, a, 0, 0, 0);
                a = __builtin_amdgcn_mfma_f32_16x16x32_bf16(al, bh, a, 0, 0, 0);
                acc[fr][fc] = a;
            }
        }
    }

    #pragma unroll
    for (int fr = 0; fr < 4; ++fr)
        #pragma unroll
        for (int fc = 0; fc < 2; ++fc) {
            int colg = col0 + wc * 32 + fc * 16 + lr;
            int rowb = row0 + wr * 64 + fr * 16 + lk * 4;
            float bv = bias[colg];
            #pragma unroll
            for (int i = 0; i < 4; ++i)
                out[(size_t)(rowb + i) * F1D + colg] = acc[fr][fc][i] + bv;
        }
}

// ---------------------------------------------------------------------------
// Fused: xa1 = gelu(pre1 @ Keff)  [f32 to global for fc2e]
//        o   = xa1 @ w            [band, from LDS]
// ---------------------------------------------------------------------------
template<int ROWS>
__global__ __launch_bounds__(256)
void kxo_kernel(const float* __restrict__ pre1, const float* __restrict__ Kb,
                const float* __restrict__ wb, const int* __restrict__ cs,
                float* __restrict__ xa1, float* __restrict__ o_out, int m)
{
    __shared__ float sKb[4][F1D];
    __shared__ float swb[4][SZD];
    __shared__ int   scs[SZD];
    __shared__ float spre[2][F1D];
    __shared__ float sxa[2][F1D];

    const int t = threadIdx.x;
    for (int i = t; i < 4 * F1D; i += 256) sKb[i >> 9][i & 511] = Kb[i];
    for (int i = t; i < 4 * SZD; i += 256) swb[i / SZD][i % SZD] = wb[i];
    if (t < SZD) scs[t] = cs[t];

    const int row_base = blockIdx.x * ROWS;
    const int rr = t >> 7;
    const int jc = t & 127;

    for (int ch = 0; ch < ROWS; ch += 2) {
        const int r0 = row_base + ch;
        __syncthreads();
        ((float4*)&spre[0][0])[t] = *(const float4*)(pre1 + (size_t)r0 * F1D + t * 4);
        __syncthreads();

        #pragma unroll
        for (int kk = 0; kk < 4; ++kk) {
            int j  = jc + (kk << 7);
            int jb = (j / m) * m;
            float s = 0.0f;
            for (int tt = 0; tt < 4; ++tt) {
                int i2 = jb + tt; if (i2 > F1D - 1) i2 = F1D - 1;
                s = fmaf(spre[rr][i2], sKb[tt][j], s);
            }
            float g = gelu_f(s);
            sxa[rr][j] = g;
            xa1[(size_t)(r0 + rr) * F1D + j] = g;
        }
        __syncthreads();

        for (int pos = t; pos < 2 * SZD; pos += 256) {
            int rr2 = pos / SZD, c = pos - rr2 * SZD;
            int s0 = scs[c];
            float s = 0.0f;
            #pragma unroll
            for (int tt = 0; tt < 4; ++tt) {
                int i2 = s0 + tt; if (i2 > F1D - 1) i2 = F1D - 1;
                s = fmaf(sxa[rr2][i2], swb[tt][c], s);
            }
            o_out[(size_t)(r0 + rr2) * SZD + c] = s;
        }
    }
}

// ---------------------------------------------------------------------------
// Fused: xa2 = gelu(pre2 @ Keff) [LDS only]; v = xa2 @ (W3*we) + b3
// ---------------------------------------------------------------------------
template<int ROWS>
__global__ __launch_bounds__(256)
void kv_kernel(const float* __restrict__ pre2, const float* __restrict__ Kb,
               const float* __restrict__ W3b, const float* __restrict__ b3,
               float* __restrict__ v_out, int m)
{
    __shared__ float sW3[15][F1D];
    __shared__ float sKb[4][F1D];
    __shared__ float sb3[F1D];
    __shared__ float spre[2][F1D];
    __shared__ float sxa[2][F1D];

    const int t = threadIdx.x;
    for (int i = t; i < 15 * F1D; i += 256) sW3[i >> 9][i & 511] = W3b[i];
    for (int i = t; i < 4 * F1D; i += 256)  sKb[i >> 9][i & 511] = Kb[i];
    for (int i = t; i < F1D; i += 256)      sb3[i] = b3[i];

    const int row_base = blockIdx.x * ROWS;
    const int rr = t >> 7;
    const int jc = t & 127;

    for (int ch = 0; ch < ROWS; ch += 2) {
        const int r0 = row_base + ch;
        __syncthreads();
        ((float4*)&spre[0][0])[t] = *(const float4*)(pre2 + (size_t)r0 * F1D + t * 4);
        __syncthreads();

        #pragma unroll
        for (int kk = 0; kk < 4; ++kk) {
            int j  = jc + (kk << 7);
            int jb = (j / m) * m;
            float s = 0.0f;
            for (int tt = 0; tt < 4; ++tt) {
                int i2 = jb + tt; if (i2 > F1D - 1) i2 = F1D - 1;
                s = fmaf(spre[rr][i2], sKb[tt][j], s);
            }
            sxa[rr][j] = gelu_f(s);
        }
        __syncthreads();

        #pragma unroll
        for (int kk = 0; kk < 4; ++kk) {
            int j = jc + (kk << 7);
            float s = sb3[j];
            #pragma unroll
            for (int d = 0; d < 15; ++d) {
                int i2 = j - 7 + d;
                if (i2 < 0) i2 = 0; if (i2 > F1D - 1) i2 = F1D - 1;
                s = fmaf(sxa[rr][i2], sW3[d][j], s);
            }
            v_out[(size_t)(r0 + rr) * F1D + j] = s;
        }
    }
}

extern "C" void kernel_launch(void* const* d_in, const int* in_sizes, int n_in,
                              void* d_out, int out_size, void* d_ws, size_t ws_size,
                              hipStream_t stream)
{
    const float* features = (const float*)d_in[0];
    const float* Wh1 = (const float*)d_in[1];
    const float* Mh1 = (const float*)d_in[2];
    const float* G1  = (const float*)d_in[3];
    const float* Wh2 = (const float*)d_in[4];
    const float* Mh2 = (const float*)d_in[5];
    const float* G2  = (const float*)d_in[6];
    const float* W1e = (const float*)d_in[7];
    const float* b1e = (const float*)d_in[8];
    const float* W2e = (const float*)d_in[9];
    const float* b2e = (const float*)d_in[10];
    const float* W3  = (const float*)d_in[11];
    const float* b3  = (const float*)d_in[12];
    const float* kn  = (const float*)d_in[13];
    const float* w   = (const float*)d_in[14];
    const float* we  = (const float*)d_in[15];

    int m = 1;
    { int s = in_sizes[13]; while (m * m < s) ++m; }   // m = sqrt(|kn|)

    // workspace (~134 MB peak; f32 activations)
    char* base = (char*)d_ws;
    size_t off = 0;
    auto alloc = [&](size_t bytes) { void* p = base + off; off += (bytes + 255) & ~255ull; return p; };
    u16*   W1h  = (u16*)alloc((size_t)F1D * FEATD * 2);
    u16*   W1l  = (u16*)alloc((size_t)F1D * FEATD * 2);
    u16*   G1h  = (u16*)alloc((size_t)F1D * FEATD * 2);
    u16*   G1l  = (u16*)alloc((size_t)F1D * FEATD * 2);
    u16*   W2h  = (u16*)alloc((size_t)F1D * F1D * 2);
    u16*   W2l  = (u16*)alloc((size_t)F1D * F1D * 2);
    u16*   G2h  = (u16*)alloc((size_t)F1D * F1D * 2);
    u16*   G2l  = (u16*)alloc((size_t)F1D * F1D * 2);
    u16*   W1eh = (u16*)alloc((size_t)F1D * 2 * F1D * 2);
    u16*   W1el = (u16*)alloc((size_t)F1D * 2 * F1D * 2);
    u16*   W2eh = (u16*)alloc((size_t)F1D * F1D * 2);
    u16*   W2el = (u16*)alloc((size_t)F1D * F1D * 2);
    float* Kb   = (float*)alloc(4 * F1D * 4);
    float* W3b  = (float*)alloc(15 * F1D * 4);
    float* wb   = (float*)alloc(4 * SZD * 4);
    int*   cs   = (int*)alloc(SZD * 4);
    float* h11  = (float*)alloc((size_t)NROWS * F1D * 4);      // 32 MB (-> pre1)
    float* lh12 = (float*)alloc((size_t)NROWS * F1D * 4);      // 32 MB (-> pre2)
    float* hb   = (float*)alloc((size_t)NROWS * 2 * F1D * 4);  // 64 MB

    float* o_out = (float*)d_out;
    float* v_out = (float*)d_out + (size_t)NROWS * SZD;
    float* xa1   = v_out;   // scratch in output; fully overwritten by kv_kernel

    // weight prep: NALU weights f16 scaled-split; fc weights bf16 split
    wprep_f16_kernel<<<(F1D * FEATD + 255) / 256, 256, 0, stream>>>(Wh1, Mh1, W1h, W1l, FEATD, F1D);
    wprep_f16_kernel<<<(F1D * FEATD + 255) / 256, 256, 0, stream>>>(G1, nullptr, G1h, G1l, FEATD, F1D);
    wprep_f16_kernel<<<(F1D * F1D + 255) / 256, 256, 0, stream>>>(Wh2, Mh2, W2h, W2l, F1D, F1D);
    wprep_f16_kernel<<<(F1D * F1D + 255) / 256, 256, 0, stream>>>(G2, nullptr, G2h, G2l, F1D, F1D);
    wprep2_kernel<<<(F1D * 2 * F1D + 255) / 256, 256, 0, stream>>>(W1e, W1eh, W1el, 2 * F1D, F1D);
    wprep2_kernel<<<(F1D * F1D + 255) / 256, 256, 0, stream>>>(W2e, W2eh, W2el, F1D, F1D);
    prep2_kernel<<<1, 512, 0, stream>>>(kn, we, W3, Kb, W3b, m);
    colrange_wband_kernel<<<1, 256, 0, stream>>>(w, cs, wb);

    dim3 gN(F1D / 64, NROWS / 64);    // (8, 256) — NALU 64x64 tiles
    dim3 gG(F1D / 64, NROWS / 128);   // (8, 128) — fc GEMM 128x64 tiles

    // layer 1: features f32 (log fused), f32 h11 / log-h12 out
    nalu_mfma_kernel<FEATD, true, true><<<gN, 256, 0, stream>>>(
        features, features, W1h, W1l, G1h, G1l, h11, lh12, F1D);
    // layer 2: h = [ha | ht] f32 out
    nalu_mfma_kernel<F1D, false, false><<<gN, 256, 0, stream>>>(
        h11, lh12, W2h, W2l, G2h, G2l, hb, hb + F1D, 2 * F1D);

    // fc1e: pre1 = h @ W1e + b1e  (pre1 overwrites h11 — dead now)
    float* pre1 = h11;
    gemm_mfma_kernel<2 * F1D><<<gG, 256, 0, stream>>>(hb, W1eh, W1el, b1e, pre1);

    // fused keff-gelu + o  (xa1 f32 for fc2e)
    kxo_kernel<8><<<NROWS / 8, 256, 0, stream>>>(pre1, Kb, wb, cs, xa1, o_out, m);

    // fc2e: pre2 = xa1 @ W2e + b2e  (lh12 dead -> reuse)
    float* pre2 = lh12;
    gemm_mfma_kernel<F1D><<<gG, 256, 0, stream>>>(xa1, W2eh, W2el, b2e, pre2);

    // fused keff-gelu + v  (v overwrites xa1 scratch after fc2e consumed it)
    kv_kernel<8><<<NROWS / 8, 256, 0, stream>>>(pre2, Kb, W3b, b3, v_out, m);
}

// Round 10
// 536.725 us; speedup vs baseline: 3.4072x; 1.0585x over previous
//
#include <hip/hip_runtime.h>
#include <hip/hip_bf16.h>
#include <hip/hip_fp16.h>

#define NROWS 16384   // B*T
#define FEATD 256
#define F1D   512
#define SZD   192     // action_dim * atoms

typedef unsigned short u16;
typedef float    f32x4  __attribute__((ext_vector_type(4)));
typedef short    bf16x8 __attribute__((ext_vector_type(8)));
typedef _Float16 f16x8  __attribute__((ext_vector_type(8)));
typedef unsigned short u16x8 __attribute__((ext_vector_type(8)));

#define LO_SCALE 2048.0f
#define LO_INV   (1.0f / 2048.0f)

__device__ __forceinline__ float sigmoid_f(float x) { return 1.0f / (1.0f + expf(-x)); }

__device__ __forceinline__ float gelu_f(float x) {
    float x3 = x * x * x;
    float inner = 0.7978845608028654f * (x + 0.044715f * x3);
    return 0.5f * x * (1.0f + tanhf(inner));
}

__device__ __forceinline__ u16 f2bf(float f) {
    unsigned u = __float_as_uint(f);
    u = (u + 0x7FFFu + ((u >> 16) & 1u)) >> 16;
    return (u16)u;
}
__device__ __forceinline__ float bf2f(u16 h) { return __uint_as_float(((unsigned)h) << 16); }

__device__ __forceinline__ u16 f2h_u(float f)  { return __half_as_ushort(__float2half(f)); }
__device__ __forceinline__ float h2f_u(u16 u)  { return __half2float(__ushort_as_half(u)); }

// f16 scaled-split: hi = f16(x); lo' = f16(2048*(x-hi)) — always normal
__device__ __forceinline__ void split8hs(float4 a, float4 b, u16x8& hi, u16x8& lo) {
    float v[8] = {a.x, a.y, a.z, a.w, b.x, b.y, b.z, b.w};
    #pragma unroll
    for (int i = 0; i < 8; ++i) {
        u16 h = f2h_u(v[i]);
        hi[i] = h;
        lo[i] = f2h_u((v[i] - h2f_u(h)) * LO_SCALE);
    }
}

// LDS offset (halves), 64B rows, XOR slot swizzle -> frag reads 2-way max
__device__ __forceinline__ int lofs(int row, int chunk) {
    return row * 32 + ((chunk ^ ((row >> 1) & 3)) << 3);
}

// XCD-contiguous block swizzle: 8 col-tiles of one row-panel -> same XCD.
// (HW round-robins linear bid across 8 XCDs; nwg % 8 == 0 in all grids here.)
__device__ __forceinline__ void xcd_tile(int TM, int& row0, int& col0) {
    int b   = blockIdx.x + gridDim.x * blockIdx.y;
    int nwg = gridDim.x * gridDim.y;
    int q   = nwg >> 3;
    int swz = (b & 7) * q + (b >> 3);
    col0 = (swz & 7) * 64;
    row0 = (swz >> 3) * TM;
}

// ---------------------------------------------------------------------------
// weight prep (f16 scaled-split, transposed [N][K]); optional tanh*sig fuse
// ---------------------------------------------------------------------------
__global__ void wprep_f16_kernel(const float* __restrict__ src, const float* __restrict__ src2,
                                 u16* __restrict__ dhi, u16* __restrict__ dlo, int Kd, int Nd)
{
    int idx = blockIdx.x * blockDim.x + threadIdx.x;
    if (idx >= Kd * Nd) return;
    int n = idx / Kd, k = idx - n * Kd;
    float v = src[(size_t)k * Nd + n];
    if (src2) v = tanhf(v) * sigmoid_f(src2[(size_t)k * Nd + n]);
    u16 h = f2h_u(v);
    dhi[idx] = h;
    dlo[idx] = f2h_u((v - h2f_u(h)) * LO_SCALE);
}

// weight prep (bf16 split, transposed): fc1e/fc2e weights
__global__ void wprep2_kernel(const float* __restrict__ src,
                              u16* __restrict__ dhi, u16* __restrict__ dlo, int Kd, int Nd)
{
    int idx = blockIdx.x * blockDim.x + threadIdx.x;
    if (idx >= Kd * Nd) return;
    int n = idx / Kd, k = idx - n * Kd;
    float v = src[(size_t)k * Nd + n];
    u16 h = f2bf(v);
    dhi[idx] = h;
    dlo[idx] = f2bf(v - bf2f(h));
}

// band compaction: Kb[4][512] (kron(I,kn)*we), W3b[15][512] ((W3*we) band)
__global__ __launch_bounds__(512)
void prep2_kernel(const float* __restrict__ kn, const float* __restrict__ we,
                  const float* __restrict__ W3,
                  float* __restrict__ Kb, float* __restrict__ W3b, int m)
{
    int j = threadIdx.x;
    if (j >= F1D) return;
    int jb = (j / m) * m;
    int jm = j - jb;
    for (int t = 0; t < 4; ++t) {
        int i = jb + t;
        float v = 0.0f;
        if (t < m && i < F1D)
            v = kn[t * m + jm] * we[(size_t)i * F1D + j];
        Kb[t * F1D + j] = v;
    }
    for (int d = 0; d < 15; ++d) {
        int i = j - 7 + d;
        float v = 0.0f;
        if (i >= 0 && i < F1D)
            v = W3[(size_t)i * F1D + j] * we[(size_t)i * F1D + j];
        W3b[d * F1D + j] = v;
    }
}

// per-column nonzero row start of w + compact band wb[4][192]
__global__ void colrange_wband_kernel(const float* __restrict__ w, int* __restrict__ cs,
                                      float* __restrict__ wb)
{
    int c = blockIdx.x * blockDim.x + threadIdx.x;
    if (c >= SZD) return;
    int s = 0, e = -1;
    for (int r = 0; r < F1D; ++r) {
        if (w[(size_t)r * SZD + c] != 0.0f) { if (e < 0) s = r; e = r; }
    }
    cs[c] = s;
    for (int t = 0; t < 4; ++t)
        wb[t * SZD + c] = (s + t <= e) ? w[(size_t)(s + t) * SZD + c] : 0.0f;
}

// ---------------------------------------------------------------------------
// NALU layer 1: f32 features in (log fused, split in-kernel);
// OUT: f16 scaled-split pairs h11(h,l) and log(|h12|+1e-7)(h,l)  [producer split]
// ---------------------------------------------------------------------------
template<int K>
__global__ __launch_bounds__(256)
void nalu_l1_kernel(const float* __restrict__ x1,
                    const u16* __restrict__ Wh, const u16* __restrict__ Wl,
                    const u16* __restrict__ Gh, const u16* __restrict__ Gl,
                    u16* __restrict__ o1h, u16* __restrict__ o1l,
                    u16* __restrict__ o2h, u16* __restrict__ o2l)
{
    __shared__ u16 A1h[64 * 32], A1l[64 * 32];
    __shared__ u16 A2h[64 * 32], A2l[64 * 32];
    __shared__ u16 BWh[64 * 32], BWl[64 * 32];
    __shared__ u16 BGh[64 * 32], BGl[64 * 32];

    const int t = threadIdx.x;
    const int lane = t & 63;
    const int wv = t >> 6;
    const int wr = wv >> 1, wc = wv & 1;
    const int lr = lane & 15, lk = lane >> 4;
    int row0, col0;
    xcd_tile(64, row0, col0);
    const int sr = t >> 2;
    const int kc = t & 3;

    f32x4 aA[2][2], aAx[2][2], aM[2][2], aMx[2][2], aG[2][2], aGx[2][2];
    #pragma unroll
    for (int i = 0; i < 2; ++i)
        #pragma unroll
        for (int j = 0; j < 2; ++j) {
            aA[i][j] = 0; aAx[i][j] = 0;
            aM[i][j] = 0; aMx[i][j] = 0;
            aG[i][j] = 0; aGx[i][j] = 0;
        }

    for (int k0 = 0; k0 < K; k0 += 32) {
        const float* px1 = x1 + (size_t)(row0 + sr) * K + k0 + kc * 8;
        float4 f0 = *(const float4*)px1;
        float4 f1 = *(const float4*)(px1 + 4);
        u16x8 v1h, v1l;
        split8hs(f0, f1, v1h, v1l);
        float4 e0, e1;
        e0.x = logf(fabsf(f0.x) + 1e-7f); e0.y = logf(fabsf(f0.y) + 1e-7f);
        e0.z = logf(fabsf(f0.z) + 1e-7f); e0.w = logf(fabsf(f0.w) + 1e-7f);
        e1.x = logf(fabsf(f1.x) + 1e-7f); e1.y = logf(fabsf(f1.y) + 1e-7f);
        e1.z = logf(fabsf(f1.z) + 1e-7f); e1.w = logf(fabsf(f1.w) + 1e-7f);
        u16x8 v2h, v2l;
        split8hs(e0, e1, v2h, v2l);
        u16x8 vwh = *(const u16x8*)(Wh + (size_t)(col0 + sr) * K + k0 + kc * 8);
        u16x8 vwl = *(const u16x8*)(Wl + (size_t)(col0 + sr) * K + k0 + kc * 8);
        u16x8 vgh = *(const u16x8*)(Gh + (size_t)(col0 + sr) * K + k0 + kc * 8);
        u16x8 vgl = *(const u16x8*)(Gl + (size_t)(col0 + sr) * K + k0 + kc * 8);

        __syncthreads();
        {
            int o = lofs(sr, kc);
            *(u16x8*)&A1h[o] = v1h;  *(u16x8*)&A1l[o] = v1l;
            *(u16x8*)&A2h[o] = v2h;  *(u16x8*)&A2l[o] = v2l;
            *(u16x8*)&BWh[o] = vwh;  *(u16x8*)&BWl[o] = vwl;
            *(u16x8*)&BGh[o] = vgh;  *(u16x8*)&BGl[o] = vgl;
        }
        __syncthreads();

        #pragma unroll
        for (int fc = 0; fc < 2; ++fc) {
            const int bo = lofs(wc * 32 + fc * 16 + lr, lk);
            f16x8 bwh = *(f16x8*)&BWh[bo];
            f16x8 bwl = *(f16x8*)&BWl[bo];
            f16x8 bgh = *(f16x8*)&BGh[bo];
            f16x8 bgl = *(f16x8*)&BGl[bo];
            #pragma unroll
            for (int fr = 0; fr < 2; ++fr) {
                const int ao = lofs(wr * 32 + fr * 16 + lr, lk);
                f16x8 a1h = *(f16x8*)&A1h[ao];
                f16x8 a1l = *(f16x8*)&A1l[ao];
                f16x8 a2h = *(f16x8*)&A2h[ao];
                f16x8 a2l = *(f16x8*)&A2l[ao];
                aA [fr][fc] = __builtin_amdgcn_mfma_f32_16x16x32_f16(a1h, bwh, aA [fr][fc], 0, 0, 0);
                aAx[fr][fc] = __builtin_amdgcn_mfma_f32_16x16x32_f16(a1h, bwl, aAx[fr][fc], 0, 0, 0);
                aAx[fr][fc] = __builtin_amdgcn_mfma_f32_16x16x32_f16(a1l, bwh, aAx[fr][fc], 0, 0, 0);
                aM [fr][fc] = __builtin_amdgcn_mfma_f32_16x16x32_f16(a2h, bwh, aM [fr][fc], 0, 0, 0);
                aMx[fr][fc] = __builtin_amdgcn_mfma_f32_16x16x32_f16(a2h, bwl, aMx[fr][fc], 0, 0, 0);
                aMx[fr][fc] = __builtin_amdgcn_mfma_f32_16x16x32_f16(a2l, bwh, aMx[fr][fc], 0, 0, 0);
                aG [fr][fc] = __builtin_amdgcn_mfma_f32_16x16x32_f16(a1h, bgh, aG [fr][fc], 0, 0, 0);
                aGx[fr][fc] = __builtin_amdgcn_mfma_f32_16x16x32_f16(a1h, bgl, aGx[fr][fc], 0, 0, 0);
                aGx[fr][fc] = __builtin_amdgcn_mfma_f32_16x16x32_f16(a1l, bgh, aGx[fr][fc], 0, 0, 0);
            }
        }
    }

    #pragma unroll
    for (int fr = 0; fr < 2; ++fr)
        #pragma unroll
        for (int fc = 0; fc < 2; ++fc) {
            int colg = col0 + wc * 32 + fc * 16 + lr;
            int rowb = row0 + wr * 32 + fr * 16 + lk * 4;
            #pragma unroll
            for (int i = 0; i < 4; ++i) {
                float a  = aA[fr][fc][i] + aAx[fr][fc][i] * LO_INV;
                float mm = aM[fr][fc][i] + aMx[fr][fc][i] * LO_INV;
                float g  = aG[fr][fc][i] + aGx[fr][fc][i] * LO_INV;
                float m_ = expf(fminf(fmaxf(mm, -20.0f), 20.0f));
                float gs = sigmoid_f(g);
                float h11v = gelu_f(a);
                float h12v = gelu_f(gs * a + (1.0f - gs) * m_);
                float lgv  = logf(fabsf(h12v) + 1e-7f);
                size_t oi = (size_t)(rowb + i) * F1D + colg;
                u16 hh = f2h_u(h11v);
                o1h[oi] = hh;
                o1l[oi] = f2h_u((h11v - h2f_u(hh)) * LO_SCALE);
                u16 lh = f2h_u(lgv);
                o2h[oi] = lh;
                o2l[oi] = f2h_u((lgv - h2f_u(lh)) * LO_SCALE);
            }
        }
}

// ---------------------------------------------------------------------------
// NALU layer 2: f16-pair inputs (pre-split by L1) -> bf16-pair h out [N][1024]
// (ha at col, ht at col+512). Zero split VALU in staging.
// ---------------------------------------------------------------------------
template<int K>
__global__ __launch_bounds__(256)
void nalu_l2_kernel(const u16* __restrict__ x1h, const u16* __restrict__ x1l,
                    const u16* __restrict__ x2h, const u16* __restrict__ x2l,
                    const u16* __restrict__ Wh, const u16* __restrict__ Wl,
                    const u16* __restrict__ Gh, const u16* __restrict__ Gl,
                    u16* __restrict__ ohh, u16* __restrict__ ohl)
{
    __shared__ u16 A1h[64 * 32], A1l[64 * 32];
    __shared__ u16 A2h[64 * 32], A2l[64 * 32];
    __shared__ u16 BWh[64 * 32], BWl[64 * 32];
    __shared__ u16 BGh[64 * 32], BGl[64 * 32];

    const int t = threadIdx.x;
    const int lane = t & 63;
    const int wv = t >> 6;
    const int wr = wv >> 1, wc = wv & 1;
    const int lr = lane & 15, lk = lane >> 4;
    int row0, col0;
    xcd_tile(64, row0, col0);
    const int sr = t >> 2;
    const int kc = t & 3;

    f32x4 aA[2][2], aAx[2][2], aM[2][2], aMx[2][2], aG[2][2], aGx[2][2];
    #pragma unroll
    for (int i = 0; i < 2; ++i)
        #pragma unroll
        for (int j = 0; j < 2; ++j) {
            aA[i][j] = 0; aAx[i][j] = 0;
            aM[i][j] = 0; aMx[i][j] = 0;
            aG[i][j] = 0; aGx[i][j] = 0;
        }

    for (int k0 = 0; k0 < K; k0 += 32) {
        const size_t arow = (size_t)(row0 + sr) * K + k0 + kc * 8;
        const size_t brow = (size_t)(col0 + sr) * K + k0 + kc * 8;
        u16x8 v1h = *(const u16x8*)(x1h + arow);
        u16x8 v1l = *(const u16x8*)(x1l + arow);
        u16x8 v2h = *(const u16x8*)(x2h + arow);
        u16x8 v2l = *(const u16x8*)(x2l + arow);
        u16x8 vwh = *(const u16x8*)(Wh + brow);
        u16x8 vwl = *(const u16x8*)(Wl + brow);
        u16x8 vgh = *(const u16x8*)(Gh + brow);
        u16x8 vgl = *(const u16x8*)(Gl + brow);

        __syncthreads();
        {
            int o = lofs(sr, kc);
            *(u16x8*)&A1h[o] = v1h;  *(u16x8*)&A1l[o] = v1l;
            *(u16x8*)&A2h[o] = v2h;  *(u16x8*)&A2l[o] = v2l;
            *(u16x8*)&BWh[o] = vwh;  *(u16x8*)&BWl[o] = vwl;
            *(u16x8*)&BGh[o] = vgh;  *(u16x8*)&BGl[o] = vgl;
        }
        __syncthreads();

        #pragma unroll
        for (int fc = 0; fc < 2; ++fc) {
            const int bo = lofs(wc * 32 + fc * 16 + lr, lk);
            f16x8 bwh = *(f16x8*)&BWh[bo];
            f16x8 bwl = *(f16x8*)&BWl[bo];
            f16x8 bgh = *(f16x8*)&BGh[bo];
            f16x8 bgl = *(f16x8*)&BGl[bo];
            #pragma unroll
            for (int fr = 0; fr < 2; ++fr) {
                const int ao = lofs(wr * 32 + fr * 16 + lr, lk);
                f16x8 a1h = *(f16x8*)&A1h[ao];
                f16x8 a1l = *(f16x8*)&A1l[ao];
                f16x8 a2h = *(f16x8*)&A2h[ao];
                f16x8 a2l = *(f16x8*)&A2l[ao];
                aA [fr][fc] = __builtin_amdgcn_mfma_f32_16x16x32_f16(a1h, bwh, aA [fr][fc], 0, 0, 0);
                aAx[fr][fc] = __builtin_amdgcn_mfma_f32_16x16x32_f16(a1h, bwl, aAx[fr][fc], 0, 0, 0);
                aAx[fr][fc] = __builtin_amdgcn_mfma_f32_16x16x32_f16(a1l, bwh, aAx[fr][fc], 0, 0, 0);
                aM [fr][fc] = __builtin_amdgcn_mfma_f32_16x16x32_f16(a2h, bwh, aM [fr][fc], 0, 0, 0);
                aMx[fr][fc] = __builtin_amdgcn_mfma_f32_16x16x32_f16(a2h, bwl, aMx[fr][fc], 0, 0, 0);
                aMx[fr][fc] = __builtin_amdgcn_mfma_f32_16x16x32_f16(a2l, bwh, aMx[fr][fc], 0, 0, 0);
                aG [fr][fc] = __builtin_amdgcn_mfma_f32_16x16x32_f16(a1h, bgh, aG [fr][fc], 0, 0, 0);
                aGx[fr][fc] = __builtin_amdgcn_mfma_f32_16x16x32_f16(a1h, bgl, aGx[fr][fc], 0, 0, 0);
                aGx[fr][fc] = __builtin_amdgcn_mfma_f32_16x16x32_f16(a1l, bgh, aGx[fr][fc], 0, 0, 0);
            }
        }
    }

    #pragma unroll
    for (int fr = 0; fr < 2; ++fr)
        #pragma unroll
        for (int fc = 0; fc < 2; ++fc) {
            int colg = col0 + wc * 32 + fc * 16 + lr;
            int rowb = row0 + wr * 32 + fr * 16 + lk * 4;
            #pragma unroll
            for (int i = 0; i < 4; ++i) {
                float a  = aA[fr][fc][i] + aAx[fr][fc][i] * LO_INV;
                float mm = aM[fr][fc][i] + aMx[fr][fc][i] * LO_INV;
                float g  = aG[fr][fc][i] + aGx[fr][fc][i] * LO_INV;
                float m_ = expf(fminf(fmaxf(mm, -20.0f), 20.0f));
                float gs = sigmoid_f(g);
                float hav = gelu_f(a);
                float htv = gelu_f(gs * a + (1.0f - gs) * m_);
                size_t base = (size_t)(rowb + i) * (2 * F1D) + colg;
                u16 ah = f2bf(hav);
                ohh[base] = ah;
                ohl[base] = f2bf(hav - bf2f(ah));
                u16 th = f2bf(htv);
                ohh[base + F1D] = th;
                ohl[base + F1D] = f2bf(htv - bf2f(th));
            }
        }
}

// ---------------------------------------------------------------------------
// GEMM + bias, bf16-pair A (pre-split by producer) @ bf16-pair B -> f32 out
// ---------------------------------------------------------------------------
template<int K>
__global__ __launch_bounds__(256)
void gemm_mfma_kernel(const u16* __restrict__ Ahp, const u16* __restrict__ Alp,
                      const u16* __restrict__ Bh, const u16* __restrict__ Bl,
                      const float* __restrict__ bias, float* __restrict__ out)
{
    __shared__ u16 Ah[128 * 32], Al[128 * 32];
    __shared__ u16 Bsh[64 * 32], Bsl[64 * 32];

    const int t = threadIdx.x;
    const int lane = t & 63;
    const int wv = t >> 6;
    const int wr = wv >> 1, wc = wv & 1;
    const int lr = lane & 15, lk = lane >> 4;
    int row0, col0;
    xcd_tile(128, row0, col0);
    const int sr = t >> 2;
    const int kc = t & 3;

    f32x4 acc[4][2];
    #pragma unroll
    for (int i = 0; i < 4; ++i)
        #pragma unroll
        for (int j = 0; j < 2; ++j) acc[i][j] = 0;

    for (int k0 = 0; k0 < K; k0 += 32) {
        u16x8 vah[2], val[2];
        #pragma unroll
        for (int p = 0; p < 2; ++p) {
            const size_t arow = (size_t)(row0 + p * 64 + sr) * K + k0 + kc * 8;
            vah[p] = *(const u16x8*)(Ahp + arow);
            val[p] = *(const u16x8*)(Alp + arow);
        }
        const size_t brow = (size_t)(col0 + sr) * K + k0 + kc * 8;
        u16x8 vbh = *(const u16x8*)(Bh + brow);
        u16x8 vbl = *(const u16x8*)(Bl + brow);

        __syncthreads();
        #pragma unroll
        for (int p = 0; p < 2; ++p) {
            int o = lofs(p * 64 + sr, kc);
            *(u16x8*)&Ah[o] = vah[p];
            *(u16x8*)&Al[o] = val[p];
        }
        {
            int o = lofs(sr, kc);
            *(u16x8*)&Bsh[o] = vbh;
            *(u16x8*)&Bsl[o] = vbl;
        }
        __syncthreads();

        #pragma unroll
        for (int fc = 0; fc < 2; ++fc) {
            const int bo = lofs(wc * 32 + fc * 16 + lr, lk);
            bf16x8 bh = *(bf16x8*)&Bsh[bo];
            bf16x8 bl = *(bf16x8*)&Bsl[bo];
            #pragma unroll
            for (int fr = 0; fr < 4; ++fr) {
                const int ao = lofs(wr * 64 + fr * 16 + lr, lk);
                bf16x8 ah = *(bf16x8*)&Ah[ao];
                bf16x8 al = *(bf16x8*)&Al[ao];
                f32x4 a = acc[fr][fc];
                a = __builtin_amdgcn_mfma_f32_16x16x32_bf16(ah, bh, a, 0, 0, 0);
                a = __builtin_amdgcn_mfma_f32_16x16x32_bf16(ah, bl, a, 0, 0, 0);
                a = __builtin_amdgcn_mfma_f32_16x16x32_bf16(al, bh, a, 0, 0, 0);
                acc[fr][fc] = a;
            }
        }
    }

    #pragma unroll
    for (int fr = 0; fr < 4; ++fr)
        #pragma unroll
        for (int fc = 0; fc < 2; ++fc) {
            int colg = col0 + wc * 32 + fc * 16 + lr;
            int rowb = row0 + wr * 64 + fr * 16 + lk * 4;
            float bv = bias[colg];
            #pragma unroll
            for (int i = 0; i < 4; ++i)
                out[(size_t)(rowb + i) * F1D + colg] = acc[fr][fc][i] + bv;
        }
}

// ---------------------------------------------------------------------------
// Fused: xa1 = gelu(pre1 @ Keff) -> bf16 pairs (for fc2e); o = xa1 @ w
// ---------------------------------------------------------------------------
template<int ROWS>
__global__ __launch_bounds__(256)
void kxo_kernel(const float* __restrict__ pre1, const float* __restrict__ Kb,
                const float* __restrict__ wb, const int* __restrict__ cs,
                u16* __restrict__ xa1h, u16* __restrict__ xa1l,
                float* __restrict__ o_out, int m)
{
    __shared__ float sKb[4][F1D];
    __shared__ float swb[4][SZD];
    __shared__ int   scs[SZD];
    __shared__ float spre[2][F1D];
    __shared__ float sxa[2][F1D];

    const int t = threadIdx.x;
    for (int i = t; i < 4 * F1D; i += 256) sKb[i >> 9][i & 511] = Kb[i];
    for (int i = t; i < 4 * SZD; i += 256) swb[i / SZD][i % SZD] = wb[i];
    if (t < SZD) scs[t] = cs[t];

    const int row_base = blockIdx.x * ROWS;
    const int rr = t >> 7;
    const int jc = t & 127;

    for (int ch = 0; ch < ROWS; ch += 2) {
        const int r0 = row_base + ch;
        __syncthreads();
        ((float4*)&spre[0][0])[t] = *(const float4*)(pre1 + (size_t)r0 * F1D + t * 4);
        __syncthreads();

        #pragma unroll
        for (int kk = 0; kk < 4; ++kk) {
            int j  = jc + (kk << 7);
            int jb = (j / m) * m;
            float s = 0.0f;
            for (int tt = 0; tt < 4; ++tt) {
                int i2 = jb + tt; if (i2 > F1D - 1) i2 = F1D - 1;
                s = fmaf(spre[rr][i2], sKb[tt][j], s);
            }
            float g = gelu_f(s);
            sxa[rr][j] = g;
            size_t oi = (size_t)(r0 + rr) * F1D + j;
            u16 gh = f2bf(g);
            xa1h[oi] = gh;
            xa1l[oi] = f2bf(g - bf2f(gh));
        }
        __syncthreads();

        for (int pos = t; pos < 2 * SZD; pos += 256) {
            int rr2 = pos / SZD, c = pos - rr2 * SZD;
            int s0 = scs[c];
            float s = 0.0f;
            #pragma unroll
            for (int tt = 0; tt < 4; ++tt) {
                int i2 = s0 + tt; if (i2 > F1D - 1) i2 = F1D - 1;
                s = fmaf(sxa[rr2][i2], swb[tt][c], s);
            }
            o_out[(size_t)(r0 + rr2) * SZD + c] = s;
        }
    }
}

// ---------------------------------------------------------------------------
// Fused: xa2 = gelu(pre2 @ Keff) [LDS only]; v = xa2 @ (W3*we) + b3
// ---------------------------------------------------------------------------
template<int ROWS>
__global__ __launch_bounds__(256)
void kv_kernel(const float* __restrict__ pre2, const float* __restrict__ Kb,
               const float* __restrict__ W3b, const float* __restrict__ b3,
               float* __restrict__ v_out, int m)
{
    __shared__ float sW3[15][F1D];
    __shared__ float sKb[4][F1D];
    __shared__ float sb3[F1D];
    __shared__ float spre[2][F1D];
    __shared__ float sxa[2][F1D];

    const int t = threadIdx.x;
    for (int i = t; i < 15 * F1D; i += 256) sW3[i >> 9][i & 511] = W3b[i];
    for (int i = t; i < 4 * F1D; i += 256)  sKb[i >> 9][i & 511] = Kb[i];
    for (int i = t; i < F1D; i += 256)      sb3[i] = b3[i];

    const int row_base = blockIdx.x * ROWS;
    const int rr = t >> 7;
    const int jc = t & 127;

    for (int ch = 0; ch < ROWS; ch += 2) {
        const int r0 = row_base + ch;
        __syncthreads();
        ((float4*)&spre[0][0])[t] = *(const float4*)(pre2 + (size_t)r0 * F1D + t * 4);
        __syncthreads();

        #pragma unroll
        for (int kk = 0; kk < 4; ++kk) {
            int j  = jc + (kk << 7);
            int jb = (j / m) * m;
            float s = 0.0f;
            for (int tt = 0; tt < 4; ++tt) {
                int i2 = jb + tt; if (i2 > F1D - 1) i2 = F1D - 1;
                s = fmaf(spre[rr][i2], sKb[tt][j], s);
            }
            sxa[rr][j] = gelu_f(s);
        }
        __syncthreads();

        #pragma unroll
        for (int kk = 0; kk < 4; ++kk) {
            int j = jc + (kk << 7);
            float s = sb3[j];
            #pragma unroll
            for (int d = 0; d < 15; ++d) {
                int i2 = j - 7 + d;
                if (i2 < 0) i2 = 0; if (i2 > F1D - 1) i2 = F1D - 1;
                s = fmaf(sxa[rr][i2], sW3[d][j], s);
            }
            v_out[(size_t)(r0 + rr) * F1D + j] = s;
        }
    }
}

extern "C" void kernel_launch(void* const* d_in, const int* in_sizes, int n_in,
                              void* d_out, int out_size, void* d_ws, size_t ws_size,
                              hipStream_t stream)
{
    const float* features = (const float*)d_in[0];
    const float* Wh1 = (const float*)d_in[1];
    const float* Mh1 = (const float*)d_in[2];
    const float* G1  = (const float*)d_in[3];
    const float* Wh2 = (const float*)d_in[4];
    const float* Mh2 = (const float*)d_in[5];
    const float* G2  = (const float*)d_in[6];
    const float* W1e = (const float*)d_in[7];
    const float* b1e = (const float*)d_in[8];
    const float* W2e = (const float*)d_in[9];
    const float* b2e = (const float*)d_in[10];
    const float* W3  = (const float*)d_in[11];
    const float* b3  = (const float*)d_in[12];
    const float* kn  = (const float*)d_in[13];
    const float* w   = (const float*)d_in[14];
    const float* we  = (const float*)d_in[15];

    int m = 1;
    { int s = in_sizes[13]; while (m * m < s) ++m; }   // m = sqrt(|kn|)

    // workspace (~134 MB peak)
    char* base = (char*)d_ws;
    size_t off = 0;
    auto alloc = [&](size_t bytes) { void* p = base + off; off += (bytes + 255) & ~255ull; return p; };
    u16*   W1h  = (u16*)alloc((size_t)F1D * FEATD * 2);
    u16*   W1l  = (u16*)alloc((size_t)F1D * FEATD * 2);
    u16*   G1h  = (u16*)alloc((size_t)F1D * FEATD * 2);
    u16*   G1l  = (u16*)alloc((size_t)F1D * FEATD * 2);
    u16*   W2h  = (u16*)alloc((size_t)F1D * F1D * 2);
    u16*   W2l  = (u16*)alloc((size_t)F1D * F1D * 2);
    u16*   G2h  = (u16*)alloc((size_t)F1D * F1D * 2);
    u16*   G2l  = (u16*)alloc((size_t)F1D * F1D * 2);
    u16*   W1eh = (u16*)alloc((size_t)F1D * 2 * F1D * 2);
    u16*   W1el = (u16*)alloc((size_t)F1D * 2 * F1D * 2);
    u16*   W2eh = (u16*)alloc((size_t)F1D * F1D * 2);
    u16*   W2el = (u16*)alloc((size_t)F1D * F1D * 2);
    float* Kb   = (float*)alloc(4 * F1D * 4);
    float* W3b  = (float*)alloc(15 * F1D * 4);
    float* wb   = (float*)alloc(4 * SZD * 4);
    int*   cs   = (int*)alloc(SZD * 4);
    u16*   h11h = (u16*)alloc((size_t)NROWS * F1D * 2);   // 16 MB  (-> pre1 region)
    u16*   h11l = (u16*)alloc((size_t)NROWS * F1D * 2);   // 16 MB
    u16*   l12h = (u16*)alloc((size_t)NROWS * F1D * 2);   // 16 MB  (-> pre2 region)
    u16*   l12l = (u16*)alloc((size_t)NROWS * F1D * 2);   // 16 MB
    u16*   hbh  = (u16*)alloc((size_t)NROWS * 2 * F1D * 2); // 32 MB
    u16*   hbl  = (u16*)alloc((size_t)NROWS * 2 * F1D * 2); // 32 MB
    // pre1/pre2 f32 (32 MB each) alias the L1-output pair regions (dead after L2)
    float* pre1 = (float*)h11h;
    float* pre2 = (float*)l12h;

    float* o_out = (float*)d_out;
    float* v_out = (float*)d_out + (size_t)NROWS * SZD;
    // xa1 bf16 pairs parked in the v-region (32 MB exactly); kv overwrites at end
    u16* xa1h = (u16*)v_out;
    u16* xa1l = xa1h + (size_t)NROWS * F1D;

    // weight prep: NALU weights f16 scaled-split; fc weights bf16 split
    wprep_f16_kernel<<<(F1D * FEATD + 255) / 256, 256, 0, stream>>>(Wh1, Mh1, W1h, W1l, FEATD, F1D);
    wprep_f16_kernel<<<(F1D * FEATD + 255) / 256, 256, 0, stream>>>(G1, nullptr, G1h, G1l, FEATD, F1D);
    wprep_f16_kernel<<<(F1D * F1D + 255) / 256, 256, 0, stream>>>(Wh2, Mh2, W2h, W2l, F1D, F1D);
    wprep_f16_kernel<<<(F1D * F1D + 255) / 256, 256, 0, stream>>>(G2, nullptr, G2h, G2l, F1D, F1D);
    wprep2_kernel<<<(F1D * 2 * F1D + 255) / 256, 256, 0, stream>>>(W1e, W1eh, W1el, 2 * F1D, F1D);
    wprep2_kernel<<<(F1D * F1D + 255) / 256, 256, 0, stream>>>(W2e, W2eh, W2el, F1D, F1D);
    prep2_kernel<<<1, 512, 0, stream>>>(kn, we, W3, Kb, W3b, m);
    colrange_wband_kernel<<<1, 256, 0, stream>>>(w, cs, wb);

    dim3 gN(F1D / 64, NROWS / 64);    // (8, 256)
    dim3 gG(F1D / 64, NROWS / 128);   // (8, 128)

    // layer 1: f32 features in, f16-pair h11 / log-h12 out
    nalu_l1_kernel<FEATD><<<gN, 256, 0, stream>>>(
        features, W1h, W1l, G1h, G1l, h11h, h11l, l12h, l12l);
    // layer 2: f16-pair in, bf16-pair h out [N,1024]
    nalu_l2_kernel<F1D><<<gN, 256, 0, stream>>>(
        h11h, h11l, l12h, l12l, W2h, W2l, G2h, G2l, hbh, hbl);

    // fc1e: pre1 = h @ W1e + b1e  (pre1 overwrites h11 pairs — dead now)
    gemm_mfma_kernel<2 * F1D><<<gG, 256, 0, stream>>>(hbh, hbl, W1eh, W1el, b1e, pre1);

    // fused keff-gelu + o  (xa1 bf16 pairs for fc2e)
    kxo_kernel<8><<<NROWS / 8, 256, 0, stream>>>(pre1, Kb, wb, cs, xa1h, xa1l, o_out, m);

    // fc2e: pre2 = xa1 @ W2e + b2e  (l12 pairs dead -> reuse)
    gemm_mfma_kernel<F1D><<<gG, 256, 0, stream>>>(xa1h, xa1l, W2eh, W2el, b2e, pre2);

    // fused keff-gelu + v  (v overwrites xa1 scratch after fc2e consumed it)
    kv_kernel<8><<<NROWS / 8, 256, 0, stream>>>(pre2, Kb, W3b, b3, v_out, m);
}